// Round 11
// baseline (41.629 us; speedup 1.0000x reference)
//
#include <hip/hip_runtime.h>

// PS-RoI-Align (torchvision ps_roi_align semantics).
// feat: [4, 784, 112, 112] fp32; rois: [K,5]; out: [K, 16, 7, 7] fp32.
//
// R10: cache-path gather, plane-per-block (no LDS, no barriers).
//   R5-R9 established: lockstep LDS-staging pins at ~2.7us/plane/CU
//   (4.65 TB/s) regardless of pipeline depth/schedule; depth-2 hurts.
//   R0 established: independent massively-parallel gathers hit 6.07 TB/s
//   on this data (but with 360 MB = 2.3x line amplification from k-major
//   ordering: 64 lanes -> 64 different planes).
//   R10 = R0's concurrency model + plane-local ordering for traffic:
//   block = one (b,c) plane (3136 blocks, 256 thr, LDS=0 -> ~12 blocks/CU).
//   All gathers of a block hit one 50 KB plane -> L1/L2 dedupe the ~7x
//   line re-touches; HBM fetch ~ feat size (157 MB). No sync at all;
//   latency absorbed by ~48 independent waves/CU.

#define PP 7
#define SR 2
#define SCALEF 0.0625f

constexpr int Cc     = 784;            // Cout * P * P
constexpr int Hh     = 112;
constexpr int Ww     = 112;
constexpr int PLANE  = Hh * Ww;        // 12544 floats = 50176 B
constexpr int TPB    = 256;

__global__ __launch_bounds__(TPB, 4) void psroi_gather_kernel(
    const float* __restrict__ feat,
    const float* __restrict__ rois,
    float* __restrict__ out,
    int K)
{
    int p  = blockIdx.x;               // plane index = b*Cc + c
    int b  = p / Cc;
    int c  = p % Cc;
    int pw = c % PP;
    int ph = (c % (PP * PP)) / PP;

    const float* __restrict__ f = feat + (size_t)p * PLANE;

    for (int k = threadIdx.x; k < K; k += TPB) {
        const float* r = rois + (size_t)k * 5;
        int rb = (int)r[0];
        if (rb != b) continue;         // ~1/4 of rois match this plane's batch

        float x1 = r[1] * SCALEF - 0.5f;
        float y1 = r[2] * SCALEF - 0.5f;
        float bsw = fmaxf(r[3] * SCALEF - 0.5f - x1, 0.1f) * (1.0f / (float)PP);
        float bsh = fmaxf(r[4] * SCALEF - 0.5f - y1, 0.1f) * (1.0f / (float)PP);

        float acc = 0.0f;
#pragma unroll
        for (int iy = 0; iy < SR; ++iy) {
            float gy = ((float)iy + 0.5f) / (float)SR;
            float y  = y1 + ((float)ph + gy) * bsh;
            bool  vy = (y >= -1.0f) && (y <= (float)Hh);
            float yc = fminf(fmaxf(y, 0.0f), (float)(Hh - 1));
            int   yl = (int)yc;            // yc >= 0 -> trunc == floor
            int   yh = min(yl + 1, Hh - 1);
            float ly = yc - (float)yl;
            float hy = 1.0f - ly;
#pragma unroll
            for (int ix = 0; ix < SR; ++ix) {
                float gx = ((float)ix + 0.5f) / (float)SR;
                float x  = x1 + ((float)pw + gx) * bsw;
                bool  vx = (x >= -1.0f) && (x <= (float)Ww);
                float xc = fminf(fmaxf(x, 0.0f), (float)(Ww - 1));
                int   xl = (int)xc;
                int   xh = min(xl + 1, Ww - 1);
                float lx = xc - (float)xl;
                float hx = 1.0f - lx;

                float v = hy * hx * f[yl * Ww + xl]
                        + hy * lx * f[yl * Ww + xh]
                        + ly * hx * f[yh * Ww + xl]
                        + ly * lx * f[yh * Ww + xh];
                acc += (vy && vx) ? v : 0.0f;
            }
        }
        out[(size_t)k * Cc + c] = acc * (1.0f / (float)(SR * SR));
    }
}

extern "C" void kernel_launch(void* const* d_in, const int* in_sizes, int n_in,
                              void* d_out, int out_size, void* d_ws, size_t ws_size,
                              hipStream_t stream) {
    const float* feat = (const float*)d_in[0];
    const float* rois = (const float*)d_in[1];
    float* out = (float*)d_out;

    int K = in_sizes[1] / 5;
    int nplanes = in_sizes[0] / PLANE;          // N * Cc = 3136
    psroi_gather_kernel<<<nplanes, TPB, 0, stream>>>(feat, rois, out, K);
}